// Round 1
// baseline (1251.268 us; speedup 1.0000x reference)
//
#include <hip/hip_runtime.h>
#include <hip/hip_bf16.h>
#include <stdint.h>

typedef unsigned short u16;
typedef __attribute__((ext_vector_type(8))) short short8;
typedef __attribute__((ext_vector_type(4))) float floatx4;

#define B_   512
#define D_   512
#define C_   100000

#define SCALE_  64.0f
#define COSM_   0.8775825618903728f
#define SINM_   0.479425538604203f
#define TH_     (-0.8775825618903728f)
#define MM_     0.2397127693021015f
#define EPS_    1e-7f
#define SHIFT_  89.6f

#define BM 256
#define BN 64

__device__ inline float wave_reduce_sum(float v) {
    v += __shfl_xor(v, 1);
    v += __shfl_xor(v, 2);
    v += __shfl_xor(v, 4);
    v += __shfl_xor(v, 8);
    v += __shfl_xor(v, 16);
    v += __shfl_xor(v, 32);
    return v;
}

__device__ inline u16 f2bf(float x) {
    union { float f; uint32_t u; } v; v.f = x;
    uint32_t r = v.u + 0x7fffu + ((v.u >> 16) & 1u);  // RNE
    return (u16)(r >> 16);
}

// RNE pack of two fp32 -> one dword of 2x bf16 (compiler emits v_cvt_pk_bf16_f32)
__device__ inline uint32_t cvt2_rn(float a, float b) {
    union { __hip_bfloat162 h; uint32_t u; } v;
    v.h = __float22bfloat162_rn(make_float2(a, b));
    return v.u;
}

// Fused: normalize embedding rows -> e_bf16, per-row phi (exact fp32 path),
// and zero-init rowsum (replaces a separate memset dispatch).
__global__ __launch_bounds__(256) void norm_e_phi_kernel(
    const float* __restrict__ emb, const float* __restrict__ w_raw,
    const int* __restrict__ gt, u16* __restrict__ e_bf16,
    float* __restrict__ phi, float* __restrict__ rowsum) {
    if (threadIdx.x < 4) rowsum[blockIdx.x * 4 + threadIdx.x] = 0.0f;
    int wv = threadIdx.x >> 6;
    int lane = threadIdx.x & 63;
    int b = blockIdx.x * 4 + wv;
    const float4* rp = (const float4*)(emb + (long)b * D_);
    float4 f0 = rp[lane], f1 = rp[lane + 64];
    float sq = f0.x*f0.x + f0.y*f0.y + f0.z*f0.z + f0.w*f0.w
             + f1.x*f1.x + f1.y*f1.y + f1.z*f1.z + f1.w*f1.w;
    sq = wave_reduce_sum(sq);
    float rn = 1.0f / sqrtf(sq);
    f0.x *= rn; f0.y *= rn; f0.z *= rn; f0.w *= rn;
    f1.x *= rn; f1.y *= rn; f1.z *= rn; f1.w *= rn;
    uint2 p0, p1;
    p0.x = (uint32_t)f2bf(f0.x) | ((uint32_t)f2bf(f0.y) << 16);
    p0.y = (uint32_t)f2bf(f0.z) | ((uint32_t)f2bf(f0.w) << 16);
    p1.x = (uint32_t)f2bf(f1.x) | ((uint32_t)f2bf(f1.y) << 16);
    p1.y = (uint32_t)f2bf(f1.z) | ((uint32_t)f2bf(f1.w) << 16);
    uint2* ob = (uint2*)(e_bf16 + (long)b * D_);
    ob[lane] = p0;
    ob[lane + 64] = p1;

    int g = gt[b];
    const float4* wp = (const float4*)(w_raw + (long)g * D_);
    float4 w0 = wp[lane], w1 = wp[lane + 64];
    float dt = f0.x*w0.x + f0.y*w0.y + f0.z*w0.z + f0.w*w0.w
             + f1.x*w1.x + f1.y*w1.y + f1.z*w1.z + f1.w*w1.w;
    float wsq = w0.x*w0.x + w0.y*w0.y + w0.z*w0.z + w0.w*w0.w
              + w1.x*w1.x + w1.y*w1.y + w1.z*w1.z + w1.w*w1.w;
    dt = wave_reduce_sum(dt);
    wsq = wave_reduce_sum(wsq);
    if (lane == 0) {
        float pos = dt / sqrtf(wsq);
        pos = fminf(fmaxf(pos, -1.0f + EPS_), 1.0f - EPS_);
        float s2 = 1.0f - pos * pos;
        s2 = fminf(fmaxf(s2, EPS_), 1.0f - EPS_);
        float sin_t = sqrtf(s2);
        float ph = pos * COSM_ - sin_t * SINM_;
        ph = (pos > TH_) ? ph : (pos - MM_);
        phi[b] = ph;
    }
}

// GEMM over raw fp32 W with inline normalization + ArcFace + exp row-sums.
// Barrier-free K-loop: the 16x16x32 bf16 B-fragment (lane n=lane&15,
// k=(lane>>4)*8+j) is 32 contiguous bytes of a row-major W row, so each
// lane loads its own B fragment straight from global (L1/L2 absorbs the
// 4x intra-block redundancy; HBM still sees one pass over W), converts
// fp32->bf16 in registers via v_cvt_pk_bf16_f32, and feeds MFMA. No LDS
// staging in the loop -> no __syncthreads -> no vmcnt(0) drain per K-step
// (that drain was the 8% MfmaUtil / 250 us bottleneck). Column norms are
// per-lane partials reduced with shfl_xor(16|32) across the quad groups.
__global__ __launch_bounds__(256, 4) void gemm_arcface_fused(
    const u16* __restrict__ a_g,     // e_bf16 [512][512]
    const float* __restrict__ w_g,   // raw weight fp32 [100000][512]
    const float* __restrict__ phi, const int* __restrict__ gt,
    float* __restrict__ rowsum) {
    __shared__ float phi_s[BM];
    __shared__ int gt_s[BM];

    int tid = threadIdx.x;
    int c0 = (blockIdx.x >> 1) * BN;
    int m0 = (blockIdx.x & 1) * BM;

    phi_s[tid] = phi[m0 + tid];
    gt_s[tid] = gt[m0 + tid];
    __syncthreads();   // only barrier in the kernel (pre-loop)

    int wv = tid >> 6, lane = tid & 63;
    int low4 = lane & 15, quad = lane >> 4;

    // A fragment base: row m0+wv*64+low4(+mi*16), k = quad*8 + kt*32
    const u16* a_base = a_g + (long)(m0 + wv * 64 + low4) * D_ + quad * 8;
    // B fragment bases: W row c0+ni*16+low4, k = quad*8 + kt*32
    const float4* bp[4];
#pragma unroll
    for (int ni = 0; ni < 4; ni++) {
        int row = min(c0 + ni * 16 + low4, C_ - 1);
        bp[ni] = (const float4*)(w_g + (long)row * D_ + quad * 8);
    }

    floatx4 acc[4][4] = {};
    float sq[4] = {0.0f, 0.0f, 0.0f, 0.0f};

#pragma unroll
    for (int kt = 0; kt < 16; kt++) {
        short8 af[4];
#pragma unroll
        for (int mi = 0; mi < 4; mi++)
            af[mi] = *(const short8*)(a_base + (long)mi * 16 * D_ + kt * 32);
        short8 bfr[4];
#pragma unroll
        for (int ni = 0; ni < 4; ni++) {
            float4 lo = bp[ni][kt * 8];
            float4 hi = bp[ni][kt * 8 + 1];
            sq[ni] += lo.x*lo.x + lo.y*lo.y + lo.z*lo.z + lo.w*lo.w
                    + hi.x*hi.x + hi.y*hi.y + hi.z*hi.z + hi.w*hi.w;
            union { short8 s; uint32_t u[4]; } bb;
            bb.u[0] = cvt2_rn(lo.x, lo.y);
            bb.u[1] = cvt2_rn(lo.z, lo.w);
            bb.u[2] = cvt2_rn(hi.x, hi.y);
            bb.u[3] = cvt2_rn(hi.z, hi.w);
            bfr[ni] = bb.s;
        }
#pragma unroll
        for (int mi = 0; mi < 4; mi++)
#pragma unroll
            for (int ni = 0; ni < 4; ni++)
                acc[mi][ni] = __builtin_amdgcn_mfma_f32_16x16x32_bf16(
                    af[mi], bfr[ni], acc[mi][ni], 0, 0, 0);
    }

    // per-column 1/||w||: quads hold disjoint k-slices of column c0+ni*16+low4
    float rnorm[4];
#pragma unroll
    for (int ni = 0; ni < 4; ni++) {
        float s = sq[ni];
        s += __shfl_xor(s, 16);
        s += __shfl_xor(s, 32);
        rnorm[ni] = 1.0f / sqrtf(s);
    }

    // epilogue: normalize, clip, reweight, gt-substitute, exp, row-reduce
#pragma unroll
    for (int mi = 0; mi < 4; mi++) {
#pragma unroll
        for (int r = 0; r < 4; r++) {
            int rl = wv * 64 + mi * 16 + quad * 4 + r;
            float ph = phi_s[rl];
            int g = gt_s[rl];
            float s = 0.0f;
#pragma unroll
            for (int ni = 0; ni < 4; ni++) {
                int cl = ni * 16 + low4;
                int c = c0 + cl;
                float v = acc[mi][ni][r] * rnorm[ni];
                v = fminf(fmaxf(v, -1.0f + EPS_), 1.0f - EPS_);
                float logit = (v > ph) ? (1.2f * v + 0.2f) : v;
                logit *= SCALE_;
                if (c == g) logit = SCALE_ * ph;
                s += (c < C_) ? __expf(logit - SHIFT_) : 0.0f;
            }
            s += __shfl_xor(s, 1);
            s += __shfl_xor(s, 2);
            s += __shfl_xor(s, 4);
            s += __shfl_xor(s, 8);
            if (low4 == 0) atomicAdd(&rowsum[m0 + rl], s);
        }
    }
}

__global__ __launch_bounds__(256) void loss_kernel(
    const float* __restrict__ rowsum, const float* __restrict__ phi,
    float* __restrict__ out) {
    __shared__ float red[4];
    int tid = threadIdx.x;
    float s = 0.0f;
    for (int b = tid; b < B_; b += 256)
        s += logf(rowsum[b]) + SHIFT_ - SCALE_ * phi[b];
    s = wave_reduce_sum(s);
    int wv = tid >> 6, lane = tid & 63;
    if (lane == 0) red[wv] = s;
    __syncthreads();
    if (tid == 0) out[0] = (red[0] + red[1] + red[2] + red[3]) * (1.0f / B_);
}

extern "C" void kernel_launch(void* const* d_in, const int* in_sizes, int n_in,
                              void* d_out, int out_size, void* d_ws, size_t ws_size,
                              hipStream_t stream) {
    const float* emb = (const float*)d_in[0];   // [512][512] f32
    const float* wgt = (const float*)d_in[1];   // [100000][512] f32
    const int* gt = (const int*)d_in[2];        // [512] int32
    float* out = (float*)d_out;

    char* ws = (char*)d_ws;
    u16* e_bf16 = (u16*)(ws);                   //   524,288 B
    float* phi = (float*)(ws + 524288);         //     2,048 B
    float* rowsum = (float*)(ws + 526336);      //     2,048 B

    norm_e_phi_kernel<<<B_ / 4, 256, 0, stream>>>(emb, wgt, gt, e_bf16, phi, rowsum);
    int nc = (C_ + BN - 1) / BN;                // 1563 c-tiles
    gemm_arcface_fused<<<nc * 2, 256, 0, stream>>>(e_bf16, wgt, phi, gt, rowsum);
    loss_kernel<<<1, 256, 0, stream>>>(rowsum, phi, out);
}

// Round 2
// 524.028 us; speedup vs baseline: 2.3878x; 2.3878x over previous
//
#include <hip/hip_runtime.h>
#include <hip/hip_bf16.h>
#include <stdint.h>

typedef unsigned short u16;
typedef __attribute__((ext_vector_type(8))) short short8;
typedef __attribute__((ext_vector_type(4))) float floatx4;

#define B_   512
#define D_   512
#define C_   100000

#define SCALE_  64.0f
#define COSM_   0.8775825618903728f
#define SINM_   0.479425538604203f
#define TH_     (-0.8775825618903728f)
#define MM_     0.2397127693021015f
#define EPS_    1e-7f
#define SHIFT_  89.6f

#define BM 256
#define BN 64

__device__ inline float wave_reduce_sum(float v) {
    v += __shfl_xor(v, 1);
    v += __shfl_xor(v, 2);
    v += __shfl_xor(v, 4);
    v += __shfl_xor(v, 8);
    v += __shfl_xor(v, 16);
    v += __shfl_xor(v, 32);
    return v;
}

__device__ inline u16 f2bf(float x) {
    union { float f; uint32_t u; } v; v.f = x;
    uint32_t r = v.u + 0x7fffu + ((v.u >> 16) & 1u);  // RNE
    return (u16)(r >> 16);
}

// RNE pack of two fp32 -> one dword of 2x bf16 (compiler emits v_cvt_pk_bf16_f32)
__device__ inline uint32_t cvt2_rn(float a, float b) {
    union { __hip_bfloat162 h; uint32_t u; } v;
    v.h = __float22bfloat162_rn(make_float2(a, b));
    return v.u;
}

// Fused: normalize embedding rows -> e_bf16, per-row phi (exact fp32 path),
// and zero-init rowsum (replaces a separate memset dispatch).
__global__ __launch_bounds__(256) void norm_e_phi_kernel(
    const float* __restrict__ emb, const float* __restrict__ w_raw,
    const int* __restrict__ gt, u16* __restrict__ e_bf16,
    float* __restrict__ phi, float* __restrict__ rowsum) {
    if (threadIdx.x < 4) rowsum[blockIdx.x * 4 + threadIdx.x] = 0.0f;
    int wv = threadIdx.x >> 6;
    int lane = threadIdx.x & 63;
    int b = blockIdx.x * 4 + wv;
    const float4* rp = (const float4*)(emb + (long)b * D_);
    float4 f0 = rp[lane], f1 = rp[lane + 64];
    float sq = f0.x*f0.x + f0.y*f0.y + f0.z*f0.z + f0.w*f0.w
             + f1.x*f1.x + f1.y*f1.y + f1.z*f1.z + f1.w*f1.w;
    sq = wave_reduce_sum(sq);
    float rn = 1.0f / sqrtf(sq);
    f0.x *= rn; f0.y *= rn; f0.z *= rn; f0.w *= rn;
    f1.x *= rn; f1.y *= rn; f1.z *= rn; f1.w *= rn;
    uint2 p0, p1;
    p0.x = (uint32_t)f2bf(f0.x) | ((uint32_t)f2bf(f0.y) << 16);
    p0.y = (uint32_t)f2bf(f0.z) | ((uint32_t)f2bf(f0.w) << 16);
    p1.x = (uint32_t)f2bf(f1.x) | ((uint32_t)f2bf(f1.y) << 16);
    p1.y = (uint32_t)f2bf(f1.z) | ((uint32_t)f2bf(f1.w) << 16);
    uint2* ob = (uint2*)(e_bf16 + (long)b * D_);
    ob[lane] = p0;
    ob[lane + 64] = p1;

    int g = gt[b];
    const float4* wp = (const float4*)(w_raw + (long)g * D_);
    float4 w0 = wp[lane], w1 = wp[lane + 64];
    float dt = f0.x*w0.x + f0.y*w0.y + f0.z*w0.z + f0.w*w0.w
             + f1.x*w1.x + f1.y*w1.y + f1.z*w1.z + f1.w*w1.w;
    float wsq = w0.x*w0.x + w0.y*w0.y + w0.z*w0.z + w0.w*w0.w
              + w1.x*w1.x + w1.y*w1.y + w1.z*w1.z + w1.w*w1.w;
    dt = wave_reduce_sum(dt);
    wsq = wave_reduce_sum(wsq);
    if (lane == 0) {
        float pos = dt / sqrtf(wsq);
        pos = fminf(fmaxf(pos, -1.0f + EPS_), 1.0f - EPS_);
        float s2 = 1.0f - pos * pos;
        s2 = fminf(fmaxf(s2, EPS_), 1.0f - EPS_);
        float sin_t = sqrtf(s2);
        float ph = pos * COSM_ - sin_t * SINM_;
        ph = (pos > TH_) ? ph : (pos - MM_);
        phi[b] = ph;
    }
}

// Barrier-free GEMM: each lane loads its own 16x16x32 B-fragment (32
// contiguous bytes of a row-major fp32 W row) straight from global,
// converts fp32->bf16 in registers (v_cvt_pk_bf16_f32), feeds MFMA.
// No LDS in the loop -> no __syncthreads -> no vmcnt(0) drain per K-step.
// launch_bounds(256,2): 256-reg budget = 64 AGPR acc + ~150 VGPR working
// set, NO SPILL (round 1's (256,4) cap of 128 spilled acc operands ->
// 1.7 GB scratch writes, 4x slower). ILP (12 indep 16B loads/K-step,
// fully unrolled, no barriers) covers latency at 2 blocks/CU.
__global__ __launch_bounds__(256, 2) void gemm_arcface_fused(
    const u16* __restrict__ a_g,     // e_bf16 [512][512]
    const float* __restrict__ w_g,   // raw weight fp32 [100000][512]
    const float* __restrict__ phi, const int* __restrict__ gt,
    float* __restrict__ rowsum) {
    __shared__ float phi_s[BM];
    __shared__ int gt_s[BM];

    int tid = threadIdx.x;
    int c0 = (blockIdx.x >> 1) * BN;
    int m0 = (blockIdx.x & 1) * BM;

    phi_s[tid] = phi[m0 + tid];
    gt_s[tid] = gt[m0 + tid];
    __syncthreads();   // only barrier in the kernel (pre-loop)

    int wv = tid >> 6, lane = tid & 63;
    int low4 = lane & 15, quad = lane >> 4;

    // A fragment base: row m0+wv*64+low4(+mi*16), k = quad*8 + kt*32
    const u16* a_base = a_g + (long)(m0 + wv * 64 + low4) * D_ + quad * 8;
    // B fragment bases: W row c0+ni*16+low4, k = quad*8 + kt*32
    const float4* bp[4];
#pragma unroll
    for (int ni = 0; ni < 4; ni++) {
        int row = min(c0 + ni * 16 + low4, C_ - 1);
        bp[ni] = (const float4*)(w_g + (long)row * D_ + quad * 8);
    }

    floatx4 acc[4][4] = {};
    float sq[4] = {0.0f, 0.0f, 0.0f, 0.0f};

#pragma unroll
    for (int kt = 0; kt < 16; kt++) {
        short8 af[4];
#pragma unroll
        for (int mi = 0; mi < 4; mi++)
            af[mi] = *(const short8*)(a_base + (long)mi * 16 * D_ + kt * 32);
        short8 bfr[4];
#pragma unroll
        for (int ni = 0; ni < 4; ni++) {
            float4 lo = bp[ni][kt * 8];
            float4 hi = bp[ni][kt * 8 + 1];
            sq[ni] += lo.x*lo.x + lo.y*lo.y + lo.z*lo.z + lo.w*lo.w
                    + hi.x*hi.x + hi.y*hi.y + hi.z*hi.z + hi.w*hi.w;
            union { short8 s; uint32_t u[4]; } bb;
            bb.u[0] = cvt2_rn(lo.x, lo.y);
            bb.u[1] = cvt2_rn(lo.z, lo.w);
            bb.u[2] = cvt2_rn(hi.x, hi.y);
            bb.u[3] = cvt2_rn(hi.z, hi.w);
            bfr[ni] = bb.s;
        }
#pragma unroll
        for (int mi = 0; mi < 4; mi++)
#pragma unroll
            for (int ni = 0; ni < 4; ni++)
                acc[mi][ni] = __builtin_amdgcn_mfma_f32_16x16x32_bf16(
                    af[mi], bfr[ni], acc[mi][ni], 0, 0, 0);
    }

    // per-column 1/||w||: quads hold disjoint k-slices of column c0+ni*16+low4
    float rnorm[4];
#pragma unroll
    for (int ni = 0; ni < 4; ni++) {
        float s = sq[ni];
        s += __shfl_xor(s, 16);
        s += __shfl_xor(s, 32);
        rnorm[ni] = 1.0f / sqrtf(s);
    }

    // epilogue: normalize, clip, reweight, gt-substitute, exp, row-reduce
#pragma unroll
    for (int mi = 0; mi < 4; mi++) {
#pragma unroll
        for (int r = 0; r < 4; r++) {
            int rl = wv * 64 + mi * 16 + quad * 4 + r;
            float ph = phi_s[rl];
            int g = gt_s[rl];
            float s = 0.0f;
#pragma unroll
            for (int ni = 0; ni < 4; ni++) {
                int cl = ni * 16 + low4;
                int c = c0 + cl;
                float v = acc[mi][ni][r] * rnorm[ni];
                v = fminf(fmaxf(v, -1.0f + EPS_), 1.0f - EPS_);
                float logit = (v > ph) ? (1.2f * v + 0.2f) : v;
                logit *= SCALE_;
                if (c == g) logit = SCALE_ * ph;
                s += (c < C_) ? __expf(logit - SHIFT_) : 0.0f;
            }
            s += __shfl_xor(s, 1);
            s += __shfl_xor(s, 2);
            s += __shfl_xor(s, 4);
            s += __shfl_xor(s, 8);
            if (low4 == 0) atomicAdd(&rowsum[m0 + rl], s);
        }
    }
}

__global__ __launch_bounds__(256) void loss_kernel(
    const float* __restrict__ rowsum, const float* __restrict__ phi,
    float* __restrict__ out) {
    __shared__ float red[4];
    int tid = threadIdx.x;
    float s = 0.0f;
    for (int b = tid; b < B_; b += 256)
        s += logf(rowsum[b]) + SHIFT_ - SCALE_ * phi[b];
    s = wave_reduce_sum(s);
    int wv = tid >> 6, lane = tid & 63;
    if (lane == 0) red[wv] = s;
    __syncthreads();
    if (tid == 0) out[0] = (red[0] + red[1] + red[2] + red[3]) * (1.0f / B_);
}

extern "C" void kernel_launch(void* const* d_in, const int* in_sizes, int n_in,
                              void* d_out, int out_size, void* d_ws, size_t ws_size,
                              hipStream_t stream) {
    const float* emb = (const float*)d_in[0];   // [512][512] f32
    const float* wgt = (const float*)d_in[1];   // [100000][512] f32
    const int* gt = (const int*)d_in[2];        // [512] int32
    float* out = (float*)d_out;

    char* ws = (char*)d_ws;
    u16* e_bf16 = (u16*)(ws);                   //   524,288 B
    float* phi = (float*)(ws + 524288);         //     2,048 B
    float* rowsum = (float*)(ws + 526336);      //     2,048 B

    norm_e_phi_kernel<<<B_ / 4, 256, 0, stream>>>(emb, wgt, gt, e_bf16, phi, rowsum);
    int nc = (C_ + BN - 1) / BN;                // 1563 c-tiles
    gemm_arcface_fused<<<nc * 2, 256, 0, stream>>>(e_bf16, wgt, phi, gt, rowsum);
    loss_kernel<<<1, 256, 0, stream>>>(rowsum, phi, out);
}